// Round 8
// baseline (572.419 us; speedup 1.0000x reference)
//
#include <hip/hip_runtime.h>
#include <hip/hip_bf16.h>
#include <math.h>

#define L_SEQ 2048
#define Dm    512
#define DI    1024
#define Nst   16
#define Kc    4
#define Rr    32
#define NL    4
#define CH    128
#define LC    (L_SEQ / CH)   // 16

typedef __attribute__((ext_vector_type(8))) short bf16x8;
typedef __attribute__((ext_vector_type(4))) float f32x4;

// ---------------- helpers ----------------
__device__ __forceinline__ float act_softplus(float x) {
    return fmaxf(x, 0.f) + log1pf(__expf(-fabsf(x)));
}
__device__ __forceinline__ float act_gelu(float x) {
    float c = 0.7978845608028654f * (x + 0.044715f * x * x * x);
    float t = 1.f - 2.f / (__expf(2.f * c) + 1.f);   // tanh(c)
    return 0.5f * x * (1.f + t);
}
__device__ __forceinline__ float silu_(float x) {
    return x / (1.f + __expf(-x));
}
__device__ __forceinline__ ushort f2bf(float f) {
    union { float f; unsigned u; } c; c.f = f;
    unsigned r = c.u + 0x7fffu + ((c.u >> 16) & 1u);
    return (ushort)(r >> 16);
}
__device__ __forceinline__ float bf2f(ushort u) {
    union { unsigned u; float f; } c; c.u = ((unsigned)u) << 16;
    return c.f;
}

// ---------------- one-shot weight cast f32 -> bf16 (all 6 tensors) ----------------
__global__ __launch_bounds__(256) void cast_all_kernel(
    const float* __restrict__ s0, ushort* __restrict__ d0, int n0,
    const float* __restrict__ s1, ushort* __restrict__ d1, int n1,
    const float* __restrict__ s2, ushort* __restrict__ d2, int n2,
    const float* __restrict__ s3, ushort* __restrict__ d3, int n3,
    const float* __restrict__ s4, ushort* __restrict__ d4, int n4_,
    const float* __restrict__ s5, ushort* __restrict__ d5, int n5)
{
    int i = blockIdx.x * 256 + threadIdx.x;
    const float* s; ushort* d;
    if (i < n0) { s = s0; d = d0; }
    else { i -= n0; if (i < n1) { s = s1; d = d1; }
    else { i -= n1; if (i < n2) { s = s2; d = d2; }
    else { i -= n2; if (i < n3) { s = s3; d = d3; }
    else { i -= n3; if (i < n4_) { s = s4; d = d4; }
    else { i -= n4_; if (i < n5) { s = s5; d = d5; } else return; } } } } }
    float4 v = ((const float4*)s)[i];
    ushort4 o;
    o.x = f2bf(v.x); o.y = f2bf(v.y); o.z = f2bf(v.z); o.w = f2bf(v.w);
    ((ushort4*)d)[i] = o;
}

// ---------------- LayerNorm (rows of 512) -> fp32 ----------------
__global__ __launch_bounds__(256) void ln_kernel(const float* __restrict__ x,
    const float* __restrict__ w, const float* __restrict__ b, float* __restrict__ y)
{
    int row = blockIdx.x;
    int i0 = threadIdx.x, i1 = threadIdx.x + 256;
    const float* xr = x + (size_t)row * Dm;
    float v0 = xr[i0], v1 = xr[i1];
    float s = v0 + v1, ss = v0 * v0 + v1 * v1;
    for (int off = 32; off; off >>= 1) { s += __shfl_down(s, off); ss += __shfl_down(ss, off); }
    __shared__ float red[10];
    int wid = threadIdx.x >> 6;
    if ((threadIdx.x & 63) == 0) { red[wid] = s; red[4 + wid] = ss; }
    __syncthreads();
    if (threadIdx.x == 0) {
        float S = red[0] + red[1] + red[2] + red[3];
        float SS = red[4] + red[5] + red[6] + red[7];
        float mu = S * (1.f / Dm);
        float var = SS * (1.f / Dm) - mu * mu;
        red[8] = mu; red[9] = rsqrtf(var + 1e-5f);
    }
    __syncthreads();
    float mu = red[8], rs = red[9];
    y[(size_t)row * Dm + i0] = (v0 - mu) * rs * w[i0] + b[i0];
    y[(size_t)row * Dm + i1] = (v1 - mu) * rs * w[i1] + b[i1];
}

// ---------------- residual add + RMSNorm (sum fp32, rms out bf16) ----------------
__global__ __launch_bounds__(256) void add_rms_kernel(const float* __restrict__ a,
    const float* __restrict__ bsrc, float* __restrict__ sum_out,
    const float* __restrict__ w, ushort* __restrict__ rms_out)
{
    int row = blockIdx.x;
    int i0 = threadIdx.x, i1 = threadIdx.x + 256;
    size_t base = (size_t)row * Dm;
    float v0 = a[base + i0], v1 = a[base + i1];
    if (bsrc) { v0 += bsrc[base + i0]; v1 += bsrc[base + i1]; }
    sum_out[base + i0] = v0; sum_out[base + i1] = v1;
    float ss = v0 * v0 + v1 * v1;
    for (int off = 32; off; off >>= 1) ss += __shfl_down(ss, off);
    __shared__ float red[5];
    if ((threadIdx.x & 63) == 0) red[threadIdx.x >> 6] = ss;
    __syncthreads();
    if (threadIdx.x == 0) red[4] = rsqrtf((red[0] + red[1] + red[2] + red[3]) * (1.f / Dm) + 1e-5f);
    __syncthreads();
    float rs = red[4];
    rms_out[base + i0] = f2bf(v0 * rs * w[i0]);
    rms_out[base + i1] = f2bf(v1 * rs * w[i1]);
}

// ---------------- fused: hout = shortcut + RMS(h+res)*wf; hn = LN(hout)*w2+b2 ----------------
__global__ __launch_bounds__(256) void final_ln2_kernel(const float* __restrict__ h,
    const float* __restrict__ res, const float* __restrict__ shortcut,
    const float* __restrict__ wf, const float* __restrict__ w2,
    const float* __restrict__ b2, float* __restrict__ hout,
    ushort* __restrict__ yb16)
{
    int row = blockIdx.x;
    int i0 = threadIdx.x, i1 = threadIdx.x + 256;
    size_t base = (size_t)row * Dm;
    float v0 = h[base + i0] + res[base + i0];
    float v1 = h[base + i1] + res[base + i1];
    float ss = v0 * v0 + v1 * v1;
    for (int off = 32; off; off >>= 1) ss += __shfl_down(ss, off);
    __shared__ float red[10];
    if ((threadIdx.x & 63) == 0) red[threadIdx.x >> 6] = ss;
    __syncthreads();
    if (threadIdx.x == 0) red[4] = rsqrtf((red[0] + red[1] + red[2] + red[3]) * (1.f / Dm) + 1e-5f);
    __syncthreads();
    float rs = red[4];
    float t0 = shortcut[base + i0] + v0 * rs * wf[i0];
    float t1 = shortcut[base + i1] + v1 * rs * wf[i1];
    hout[base + i0] = t0;
    hout[base + i1] = t1;
    __syncthreads();
    float s = t0 + t1, ss2 = t0 * t0 + t1 * t1;
    for (int off = 32; off; off >>= 1) { s += __shfl_down(s, off); ss2 += __shfl_down(ss2, off); }
    int wid = threadIdx.x >> 6;
    if ((threadIdx.x & 63) == 0) { red[wid] = s; red[5 + wid] = ss2; }
    __syncthreads();
    if (threadIdx.x == 0) {
        float S = red[0] + red[1] + red[2] + red[3];
        float SS = red[5] + red[6] + red[7] + red[8];
        float mu = S * (1.f / Dm);
        float var = SS * (1.f / Dm) - mu * mu;
        red[4] = mu; red[9] = rsqrtf(var + 1e-5f);
    }
    __syncthreads();
    float mu = red[4], rsig = red[9];
    yb16[base + i0] = f2bf((t0 - mu) * rsig * w2[i0] + b2[i0]);
    yb16[base + i1] = f2bf((t1 - mu) * rsig * w2[i1] + b2[i1]);
}

// ---------------- MFMA bf16 GEMM: C(M,N) = A(M,K) * W(N,K)^T ----------------
// EPI: 0 = f32 store; 1 = bf16 store; 2 = bias+gelu -> bf16; 4 = bias+addsrc -> f32
// KS>1: split-K over blockIdx.z, fp32 partials at Cout + z*split_stride (EPI must be 0)
template<int BM, int BN, int BK, int EPI, int KS = 1>
__global__ __launch_bounds__(256) void gemm_mfma(
    const ushort* __restrict__ A, int lda,
    const ushort* __restrict__ W, int K,
    void* __restrict__ Cout, int ldc,
    const float* __restrict__ bias, const float* __restrict__ addsrc,
    size_t split_stride)
{
    constexpr int ROWB  = BK * 2;            // row bytes in LDS tile
    constexpr int SMASK = (ROWB / 16) - 1;   // 16B slots per row - 1
    constexpr int KK    = BK / 32;           // mfma k-chunks per step
    constexpr int WM = BM / 2, WN = BN / 2;
    constexpr int FM = WM / 16, FN = WN / 16;
    constexpr int ISS_A = (BM * ROWB) / 4096;
    constexpr int ISS_W = (BN * ROWB) / 4096;

    __shared__ __align__(16) ushort As[BM * BK];
    __shared__ __align__(16) ushort Ws[BN * BK];

    int tid = threadIdx.x;
    int wave = tid >> 6, lane = tid & 63;
    int wr = wave >> 1, wc = wave & 1;
    int l16 = lane & 15, lk = lane >> 4;
    int bm = blockIdx.y * BM, bn = blockIdx.x * BN;

    int kbeg = 0, kend = K;
    float* coutf = (float*)Cout;
    if constexpr (KS > 1) {
        int Kper = K / KS;
        kbeg = blockIdx.z * Kper; kend = kbeg + Kper;
        coutf += split_stride * blockIdx.z;
    }

    const ushort* srcA[ISS_A];
    const ushort* srcW[ISS_W];
    #pragma unroll
    for (int s = 0; s < ISS_A; ++s) {
        int off = s * 4096 + wave * 1024 + lane * 16;
        int row = off / ROWB;
        int slot = (off % ROWB) >> 4;
        int col = ((slot ^ (row & SMASK)) << 3);
        srcA[s] = A + (size_t)(bm + row) * lda + col;
    }
    #pragma unroll
    for (int s = 0; s < ISS_W; ++s) {
        int off = s * 4096 + wave * 1024 + lane * 16;
        int row = off / ROWB;
        int slot = (off % ROWB) >> 4;
        int col = ((slot ^ (row & SMASK)) << 3);
        srcW[s] = W + (size_t)(bn + row) * K + col;
    }
    int aoff[FM][KK], woff[FN][KK];
    #pragma unroll
    for (int i = 0; i < FM; ++i) {
        int row = wr * WM + i * 16 + l16;
        #pragma unroll
        for (int kk = 0; kk < KK; ++kk)
            aoff[i][kk] = row * BK + ((((kk << 2) | lk) ^ (row & SMASK)) << 3);
    }
    #pragma unroll
    for (int j = 0; j < FN; ++j) {
        int row = wc * WN + j * 16 + l16;
        #pragma unroll
        for (int kk = 0; kk < KK; ++kk)
            woff[j][kk] = row * BK + ((((kk << 2) | lk) ^ (row & SMASK)) << 3);
    }

    f32x4 acc[FM][FN] = {};

    for (int k0 = kbeg; k0 < kend; k0 += BK) {
        #pragma unroll
        for (int s = 0; s < ISS_A; ++s)
            __builtin_amdgcn_global_load_lds(
                (const __attribute__((address_space(1))) void*)(srcA[s] + k0),
                (__attribute__((address_space(3))) void*)((char*)As + s * 4096 + wave * 1024),
                16, 0, 0);
        #pragma unroll
        for (int s = 0; s < ISS_W; ++s)
            __builtin_amdgcn_global_load_lds(
                (const __attribute__((address_space(1))) void*)(srcW[s] + k0),
                (__attribute__((address_space(3))) void*)((char*)Ws + s * 4096 + wave * 1024),
                16, 0, 0);
        __syncthreads();
        #pragma unroll
        for (int kk = 0; kk < KK; ++kk) {
            bf16x8 af[FM], wf[FN];
            #pragma unroll
            for (int i = 0; i < FM; ++i) af[i] = *(const bf16x8*)(As + aoff[i][kk]);
            #pragma unroll
            for (int j = 0; j < FN; ++j) wf[j] = *(const bf16x8*)(Ws + woff[j][kk]);
            #pragma unroll
            for (int i = 0; i < FM; ++i)
                #pragma unroll
                for (int j = 0; j < FN; ++j)
                    acc[i][j] = __builtin_amdgcn_mfma_f32_16x16x32_bf16(af[i], wf[j], acc[i][j], 0, 0, 0);
        }
        __syncthreads();
    }

    int orow0 = bm + wr * WM, ocol0 = bn + wc * WN;
    #pragma unroll
    for (int j = 0; j < FN; ++j) {
        int col = ocol0 + j * 16 + l16;
        float bj = 0.f;
        if constexpr (EPI == 2 || EPI == 4) bj = bias[col];
        #pragma unroll
        for (int i = 0; i < FM; ++i) {
            #pragma unroll
            for (int r = 0; r < 4; ++r) {
                int row = orow0 + i * 16 + lk * 4 + r;
                float v = acc[i][j][r];
                if constexpr (EPI == 0) {
                    coutf[(size_t)row * ldc + col] = v;
                } else if constexpr (EPI == 1) {
                    ((ushort*)Cout)[(size_t)row * ldc + col] = f2bf(v);
                } else if constexpr (EPI == 2) {
                    ((ushort*)Cout)[(size_t)row * ldc + col] = f2bf(act_gelu(v + bj));
                } else if constexpr (EPI == 4) {
                    ((float*)Cout)[(size_t)row * ldc + col] = v + bj + addsrc[(size_t)row * ldc + col];
                }
            }
        }
    }
}

// ---------------- x_proj finish: sum split-K partials -> dbc(B,C) fp32 + delta bf16 ----------------
// delta[t,d] = softplus( sum_r dt[t,r]*w_dt[d,r] + b[d] ), dt = cols 0..31 of summed partials
__global__ __launch_bounds__(256) void xfin_kernel(
    const float* __restrict__ part, const ushort* __restrict__ wdt,
    const float* __restrict__ dtb, float* __restrict__ dbc,
    ushort* __restrict__ delta_bf)
{
    __shared__ float sdt[8][32];
    int tid = threadIdx.x;
    int t0 = blockIdx.x * 8;
    const int S = L_SEQ * 64;
    #pragma unroll
    for (int i = tid; i < 512; i += 256) {
        int tt = i >> 6, c = i & 63;
        int idx = (t0 + tt) * 64 + c;
        float s = part[idx] + part[idx + S] + part[idx + 2 * S] + part[idx + 3 * S];
        if (c < 32) sdt[tt][c] = s;
        else dbc[idx] = s;
    }
    __syncthreads();
    int d0 = tid * 4;
    bf16x8 w[4][4];
    float b4[4];
    #pragma unroll
    for (int q = 0; q < 4; ++q) {
        b4[q] = dtb[d0 + q];
        #pragma unroll
        for (int p = 0; p < 4; ++p)
            w[q][p] = *(const bf16x8*)(wdt + (size_t)(d0 + q) * 32 + p * 8);
    }
    for (int tt = 0; tt < 8; ++tt) {
        float acc[4] = { b4[0], b4[1], b4[2], b4[3] };
        #pragma unroll
        for (int p = 0; p < 4; ++p)
            #pragma unroll
            for (int e = 0; e < 8; ++e) {
                float sv = sdt[tt][p * 8 + e];
                #pragma unroll
                for (int q = 0; q < 4; ++q)
                    acc[q] = fmaf(sv, bf2f((ushort)w[q][p][e]), acc[q]);
            }
        ushort4 o;
        o.x = f2bf(act_softplus(acc[0]));
        o.y = f2bf(act_softplus(acc[1]));
        o.z = f2bf(act_softplus(acc[2]));
        o.w = f2bf(act_softplus(acc[3]));
        *(ushort4*)(delta_bf + (size_t)(t0 + tt) * DI + d0) = o;
    }
}

// ---------------- causal depthwise conv (K=4) + silu, vectorized bf16x8 ----------------
__global__ __launch_bounds__(256) void conv_silu_kernel(const ushort* __restrict__ xz,
    const float* __restrict__ cw, const float* __restrict__ cb, ushort* __restrict__ xc)
{
    int g = blockIdx.x * 256 + threadIdx.x;   // over L*DI/8
    int e = g * 8;
    int d0 = e & (DI - 1);
    int t = e >> 10;
    float acc[8];
    #pragma unroll
    for (int q = 0; q < 8; ++q) acc[q] = cb[d0 + q];
    float4 cwv[8];
    #pragma unroll
    for (int q = 0; q < 8; ++q) cwv[q] = *(const float4*)(cw + (size_t)(d0 + q) * 4);
    #pragma unroll
    for (int k = 0; k < 4; ++k) {
        int tt = t + k - 3;
        if (tt >= 0) {
            bf16x8 xv = *(const bf16x8*)(xz + (size_t)tt * (2 * DI) + d0);
            #pragma unroll
            for (int q = 0; q < 8; ++q) {
                float wk = (k == 0) ? cwv[q].x : (k == 1) ? cwv[q].y : (k == 2) ? cwv[q].z : cwv[q].w;
                acc[q] = fmaf(wk, bf2f((ushort)xv[q]), acc[q]);
            }
        }
    }
    bf16x8 o;
    #pragma unroll
    for (int q = 0; q < 8; ++q) o[q] = (short)f2bf(silu_(acc[q]));
    *(bf16x8*)(xc + e) = o;
}

// ---------------- 3-phase chunked SSM scan, 16 n-states per thread ----------------
__global__ __launch_bounds__(256) void scan_chunk_kernel(
    const ushort* __restrict__ delta, const ushort* __restrict__ u,
    const float* __restrict__ dbc, const float* __restrict__ A_log,
    float* __restrict__ hend, float* __restrict__ aprod)
{
    __shared__ float bs[LC][16];
    int tid = threadIdx.x;
    int c = blockIdx.x;
    int d = blockIdx.y * 256 + tid;
    int t0 = c * LC;
    {
        int tt = tid >> 4, nn = tid & 15;
        bs[tt][nn] = dbc[(size_t)(t0 + tt) * 64 + 32 + nn];
    }
    float A2[16];
    {
        float a[16];
        #pragma unroll
        for (int q = 0; q < 4; ++q)
            *(float4*)(a + q * 4) = ((const float4*)(A_log + (size_t)d * 16))[q];
        #pragma unroll
        for (int n = 0; n < 16; ++n)
            A2[n] = -__expf(a[n]) * 1.44269504f;   // A * log2(e)
    }
    float h[16], ap[16];
    #pragma unroll
    for (int n = 0; n < 16; ++n) { h[n] = 0.f; ap[n] = 1.f; }
    __syncthreads();
    for (int tt = 0; tt < LC; ++tt) {
        int t = t0 + tt;
        float dt_ = bf2f(delta[(size_t)t * DI + d]);
        float du = dt_ * bf2f(u[(size_t)t * DI + d]);
        #pragma unroll
        for (int n = 0; n < 16; ++n) {
            float dA = exp2f(dt_ * A2[n]);
            h[n] = fmaf(dA, h[n], du * bs[tt][n]);
            ap[n] *= dA;
        }
    }
    size_t base = ((size_t)c * DI + d) * 16;
    #pragma unroll
    for (int q = 0; q < 4; ++q) {
        ((float4*)(hend + base))[q]  = *(float4*)(h + q * 4);
        ((float4*)(aprod + base))[q] = *(float4*)(ap + q * 4);
    }
}

// Phase B: 64-lane wave scan over chunk pairs; (a,h)∘(a',h') = (a·a', a'·h + h')
__global__ __launch_bounds__(256) void chunk_prefix_kernel(
    const float* __restrict__ hend, float* __restrict__ aprod_hin)
{
    int lane = threadIdx.x & 63;
    int wave = threadIdx.x >> 6;
    int j = blockIdx.x * 4 + wave;           // (d*16+n) index
    size_t o0 = (size_t)(2 * lane) * (DI * Nst) + j;
    size_t o1 = o0 + DI * Nst;
    float a0 = aprod_hin[o0], h0 = hend[o0];
    float a1 = aprod_hin[o1], h1 = hend[o1];
    float pa = a0 * a1;
    float ph = fmaf(a1, h0, h1);             // pair-combined
    #pragma unroll
    for (int off = 1; off < 64; off <<= 1) {
        float sa = __shfl_up(pa, off);
        float sh = __shfl_up(ph, off);
        if (lane >= off) { ph = fmaf(pa, sh, ph); pa = sa * pa; }
    }
    float eh = __shfl_up(ph, 1);             // exclusive prefix h
    if (lane == 0) eh = 0.f;
    aprod_hin[o0] = eh;                      // h_in for chunk 2*lane
    aprod_hin[o1] = fmaf(a0, eh, h0);        // h_in for chunk 2*lane+1
}

__global__ __launch_bounds__(256) void scan_apply_kernel(
    const ushort* __restrict__ delta, const ushort* __restrict__ u,
    const float* __restrict__ dbc, const float* __restrict__ A_log,
    const float* __restrict__ Dp, const ushort* __restrict__ xz,
    const float* __restrict__ hin, ushort* __restrict__ y)
{
    __shared__ float bs[LC][16], cs[LC][16];
    int tid = threadIdx.x;
    int c = blockIdx.x;
    int d = blockIdx.y * 256 + tid;
    int t0 = c * LC;
    #pragma unroll
    for (int i = tid; i < LC * 32; i += 256) {
        int tt = i >> 5, k = i & 31;
        float v = dbc[(size_t)(t0 + tt) * 64 + 32 + k];
        if (k < 16) bs[tt][k] = v; else cs[tt][k - 16] = v;
    }
    float A2[16];
    {
        float a[16];
        #pragma unroll
        for (int q = 0; q < 4; ++q)
            *(float4*)(a + q * 4) = ((const float4*)(A_log + (size_t)d * 16))[q];
        #pragma unroll
        for (int n = 0; n < 16; ++n)
            A2[n] = -__expf(a[n]) * 1.44269504f;
    }
    float h[16];
    size_t base = ((size_t)c * DI + d) * 16;
    #pragma unroll
    for (int q = 0; q < 4; ++q)
        *(float4*)(h + q * 4) = ((const float4*)(hin + base))[q];
    float Dval = Dp[d];
    __syncthreads();
    for (int tt = 0; tt < LC; ++tt) {
        int t = t0 + tt;
        float dt_ = bf2f(delta[(size_t)t * DI + d]);
        float u_  = bf2f(u[(size_t)t * DI + d]);
        float du  = dt_ * u_;
        float acc = 0.f;
        #pragma unroll
        for (int n = 0; n < 16; ++n) {
            float dA = exp2f(dt_ * A2[n]);
            h[n] = fmaf(dA, h[n], du * bs[tt][n]);
            acc = fmaf(h[n], cs[tt][n], acc);
        }
        float z = bf2f(xz[(size_t)t * (2 * DI) + DI + d]);
        y[(size_t)t * DI + d] = f2bf((acc + u_ * Dval) * silu_(z));
    }
}

extern "C" void kernel_launch(void* const* d_in, const int* in_sizes, int n_in,
                              void* d_out, int out_size, void* d_ws, size_t ws_size,
                              hipStream_t stream)
{
    const float* hidden     = (const float*)d_in[0];
    const float* ln1_w      = (const float*)d_in[1];
    const float* ln1_b      = (const float*)d_in[2];
    const float* in_proj_w  = (const float*)d_in[3];
    const float* conv_w     = (const float*)d_in[4];
    const float* conv_b     = (const float*)d_in[5];
    const float* x_proj_w   = (const float*)d_in[6];
    const float* dt_proj_w  = (const float*)d_in[7];
    const float* dt_proj_b  = (const float*)d_in[8];
    const float* A_log      = (const float*)d_in[9];
    const float* D_param    = (const float*)d_in[10];
    const float* out_proj_w = (const float*)d_in[11];
    const float* block_norm_w = (const float*)d_in[12];
    const float* norm_f_w   = (const float*)d_in[13];
    const float* ln2_w      = (const float*)d_in[14];
    const float* ln2_b      = (const float*)d_in[15];
    const float* fc1_w      = (const float*)d_in[16];
    const float* fc1_b      = (const float*)d_in[17];
    const float* fc2_w      = (const float*)d_in[18];
    const float* fc2_b      = (const float*)d_in[19];

    char* P = (char*)d_ws;
    auto alloc = [&](size_t bytes) { char* r = P; P += (bytes + 255) & ~(size_t)255; return r; };
    float* h      = (float*)alloc((size_t)L_SEQ * Dm * 4);          // 4MB
    float* hout   = (float*)alloc((size_t)L_SEQ * Dm * 4);          // 4MB (adjacent to h)
    float* res    = (float*)alloc((size_t)L_SEQ * Dm * 4);
    float* dbc    = (float*)alloc((size_t)L_SEQ * 64 * 4);
    float* part   = (float*)alloc((size_t)4 * L_SEQ * 64 * 4);      // x_proj split-K partials
    float* aprod  = (float*)alloc((size_t)CH * DI * Nst * 4);       // 8MB; becomes hin in place
    ushort* delta_bf = (ushort*)alloc((size_t)L_SEQ * DI * 2);
    ushort* hn_bf = (ushort*)alloc((size_t)L_SEQ * Dm * 2);
    ushort* xz_bf = (ushort*)alloc((size_t)L_SEQ * 2 * DI * 2);
    ushort* xc_bf = (ushort*)alloc((size_t)L_SEQ * DI * 2);
    ushort* yb_bf = (ushort*)alloc((size_t)L_SEQ * DI * 2);
    ushort* w_in  = (ushort*)alloc((size_t)NL * 2 * DI * Dm * 2);
    ushort* w_out = (ushort*)alloc((size_t)NL * Dm * DI * 2);
    ushort* w_x   = (ushort*)alloc((size_t)NL * 64 * DI * 2);
    ushort* w_dt  = (ushort*)alloc((size_t)NL * DI * Rr * 2);
    ushort* w_fc1 = (ushort*)alloc((size_t)(4 * Dm) * Dm * 2);
    ushort* w_fc2 = (ushort*)alloc((size_t)Dm * (4 * Dm) * 2);
    float* hend = h;      // 8MB over h+hout (both dead during scan), CH*DI*16*4 = 8MB
    float* out  = (float*)d_out;

    // single fused weight cast (all layers, all 6 tensors)
    {
        int n0 = NL * 2 * DI * Dm / 4, n1 = NL * Dm * DI / 4, n2 = NL * 64 * DI / 4;
        int n3 = NL * DI * Rr / 4, n4_ = 4 * Dm * Dm / 4, n5 = Dm * 4 * Dm / 4;
        int tot = n0 + n1 + n2 + n3 + n4_ + n5;
        cast_all_kernel<<<(tot + 255) / 256, 256, 0, stream>>>(
            in_proj_w, w_in, n0, out_proj_w, w_out, n1, x_proj_w, w_x, n2,
            dt_proj_w, w_dt, n3, fc1_w, w_fc1, n4_, fc2_w, w_fc2, n5);
    }

    ln_kernel<<<L_SEQ, 256, 0, stream>>>(hidden, ln1_w, ln1_b, h);

    dim3 gscan(CH, DI / 256);   // 128 x 4 = 512 blocks
    for (int i = 0; i < NL; ++i) {
        add_rms_kernel<<<L_SEQ, 256, 0, stream>>>(h, i ? res : nullptr, res,
                                                  block_norm_w + i * Dm, hn_bf);
        // in_proj: M=2048 N=2048 K=512 -> bf16 xz
        gemm_mfma<128, 128, 128, 1><<<dim3(2 * DI / 128, L_SEQ / 128), 256, 0, stream>>>(
            hn_bf, Dm, w_in + (size_t)i * 2 * DI * Dm, Dm, xz_bf, 2 * DI, nullptr, nullptr, 0);
        conv_silu_kernel<<<(L_SEQ * DI / 8) / 256, 256, 0, stream>>>(
            xz_bf, conv_w + i * DI * Kc, conv_b + i * DI, xc_bf);
        // x_proj: M=2048 N=64 K=1024, split-K=4 -> fp32 partials
        gemm_mfma<64, 64, 64, 0, 4><<<dim3(1, L_SEQ / 64, 4), 256, 0, stream>>>(
            xc_bf, DI, w_x + (size_t)i * 64 * DI, DI, part, 64, nullptr, nullptr,
            (size_t)L_SEQ * 64);
        // finish: dbc(B,C) + delta = softplus(dt @ w_dt^T + b) -> bf16
        xfin_kernel<<<L_SEQ / 8, 256, 0, stream>>>(part, w_dt + (size_t)i * DI * Rr,
                                        dt_proj_b + i * DI, dbc, delta_bf);
        // 3-phase chunked scan
        scan_chunk_kernel<<<gscan, 256, 0, stream>>>(delta_bf, xc_bf, dbc,
                                        A_log + (size_t)i * DI * Nst, hend, aprod);
        chunk_prefix_kernel<<<(DI * Nst) / 4, 256, 0, stream>>>(hend, aprod);
        scan_apply_kernel<<<gscan, 256, 0, stream>>>(delta_bf, xc_bf, dbc,
                                        A_log + (size_t)i * DI * Nst,
                                        D_param + i * DI, xz_bf, aprod, yb_bf);
        // out_proj: M=2048 N=512 K=1024 -> fp32 h
        gemm_mfma<64, 64, 128, 0><<<dim3(Dm / 64, L_SEQ / 64), 256, 0, stream>>>(
            yb_bf, DI, w_out + (size_t)i * Dm * DI, DI, h, Dm, nullptr, nullptr, 0);
    }

    final_ln2_kernel<<<L_SEQ, 256, 0, stream>>>(h, res, hidden, norm_f_w,
                                                ln2_w, ln2_b, hout, hn_bf);
    // fc1: M=2048 N=2048 K=512, bias+gelu -> bf16 (reuse xz_bf)
    gemm_mfma<128, 128, 128, 2><<<dim3(2048 / 128, L_SEQ / 128), 256, 0, stream>>>(
        hn_bf, Dm, w_fc1, Dm, xz_bf, 2048, fc1_b, nullptr, 0);
    // fc2: M=2048 N=512 K=2048, bias+add(hout) -> fp32 out
    gemm_mfma<64, 64, 128, 4><<<dim3(Dm / 64, L_SEQ / 64), 256, 0, stream>>>(
        xz_bf, 2048, w_fc2, 2048, out, Dm, fc2_b, hout, 0);
}

// Round 9
// 456.915 us; speedup vs baseline: 1.2528x; 1.2528x over previous
//
#include <hip/hip_runtime.h>
#include <hip/hip_bf16.h>
#include <math.h>

#define L_SEQ 2048
#define Dm    512
#define DI    1024
#define Nst   16
#define Kc    4
#define Rr    32
#define NL    4
#define CH    128
#define LC    (L_SEQ / CH)   // 16

typedef __attribute__((ext_vector_type(8))) short bf16x8;
typedef __attribute__((ext_vector_type(4))) float f32x4;

// ---------------- helpers ----------------
__device__ __forceinline__ float act_softplus(float x) {
    return fmaxf(x, 0.f) + log1pf(__expf(-fabsf(x)));
}
__device__ __forceinline__ float act_gelu(float x) {
    float c = 0.7978845608028654f * (x + 0.044715f * x * x * x);
    float t = 1.f - 2.f / (__expf(2.f * c) + 1.f);   // tanh(c)
    return 0.5f * x * (1.f + t);
}
__device__ __forceinline__ float silu_(float x) {
    return x / (1.f + __expf(-x));
}
__device__ __forceinline__ ushort f2bf(float f) {
    union { float f; unsigned u; } c; c.f = f;
    unsigned r = c.u + 0x7fffu + ((c.u >> 16) & 1u);
    return (ushort)(r >> 16);
}
__device__ __forceinline__ float bf2f(ushort u) {
    union { unsigned u; float f; } c; c.u = ((unsigned)u) << 16;
    return c.f;
}

// ---------------- one-shot weight cast f32 -> bf16 (all 6 tensors) ----------------
__global__ __launch_bounds__(256) void cast_all_kernel(
    const float* __restrict__ s0, ushort* __restrict__ d0, int n0,
    const float* __restrict__ s1, ushort* __restrict__ d1, int n1,
    const float* __restrict__ s2, ushort* __restrict__ d2, int n2,
    const float* __restrict__ s3, ushort* __restrict__ d3, int n3,
    const float* __restrict__ s4, ushort* __restrict__ d4, int n4_,
    const float* __restrict__ s5, ushort* __restrict__ d5, int n5)
{
    int i = blockIdx.x * 256 + threadIdx.x;
    const float* s; ushort* d;
    if (i < n0) { s = s0; d = d0; }
    else { i -= n0; if (i < n1) { s = s1; d = d1; }
    else { i -= n1; if (i < n2) { s = s2; d = d2; }
    else { i -= n2; if (i < n3) { s = s3; d = d3; }
    else { i -= n3; if (i < n4_) { s = s4; d = d4; }
    else { i -= n4_; if (i < n5) { s = s5; d = d5; } else return; } } } } }
    float4 v = ((const float4*)s)[i];
    ushort4 o;
    o.x = f2bf(v.x); o.y = f2bf(v.y); o.z = f2bf(v.z); o.w = f2bf(v.w);
    ((ushort4*)d)[i] = o;
}

// ---------------- LayerNorm (rows of 512) -> fp32 ----------------
__global__ __launch_bounds__(256) void ln_kernel(const float* __restrict__ x,
    const float* __restrict__ w, const float* __restrict__ b, float* __restrict__ y)
{
    int row = blockIdx.x;
    int i0 = threadIdx.x, i1 = threadIdx.x + 256;
    const float* xr = x + (size_t)row * Dm;
    float v0 = xr[i0], v1 = xr[i1];
    float s = v0 + v1, ss = v0 * v0 + v1 * v1;
    for (int off = 32; off; off >>= 1) { s += __shfl_down(s, off); ss += __shfl_down(ss, off); }
    __shared__ float red[10];
    int wid = threadIdx.x >> 6;
    if ((threadIdx.x & 63) == 0) { red[wid] = s; red[4 + wid] = ss; }
    __syncthreads();
    if (threadIdx.x == 0) {
        float S = red[0] + red[1] + red[2] + red[3];
        float SS = red[4] + red[5] + red[6] + red[7];
        float mu = S * (1.f / Dm);
        float var = SS * (1.f / Dm) - mu * mu;
        red[8] = mu; red[9] = rsqrtf(var + 1e-5f);
    }
    __syncthreads();
    float mu = red[8], rs = red[9];
    y[(size_t)row * Dm + i0] = (v0 - mu) * rs * w[i0] + b[i0];
    y[(size_t)row * Dm + i1] = (v1 - mu) * rs * w[i1] + b[i1];
}

// ---------------- residual add + RMSNorm (sum fp32, rms out bf16) ----------------
__global__ __launch_bounds__(256) void add_rms_kernel(const float* __restrict__ a,
    const float* __restrict__ bsrc, float* __restrict__ sum_out,
    const float* __restrict__ w, ushort* __restrict__ rms_out)
{
    int row = blockIdx.x;
    int i0 = threadIdx.x, i1 = threadIdx.x + 256;
    size_t base = (size_t)row * Dm;
    float v0 = a[base + i0], v1 = a[base + i1];
    if (bsrc) { v0 += bsrc[base + i0]; v1 += bsrc[base + i1]; }
    sum_out[base + i0] = v0; sum_out[base + i1] = v1;
    float ss = v0 * v0 + v1 * v1;
    for (int off = 32; off; off >>= 1) ss += __shfl_down(ss, off);
    __shared__ float red[5];
    if ((threadIdx.x & 63) == 0) red[threadIdx.x >> 6] = ss;
    __syncthreads();
    if (threadIdx.x == 0) red[4] = rsqrtf((red[0] + red[1] + red[2] + red[3]) * (1.f / Dm) + 1e-5f);
    __syncthreads();
    float rs = red[4];
    rms_out[base + i0] = f2bf(v0 * rs * w[i0]);
    rms_out[base + i1] = f2bf(v1 * rs * w[i1]);
}

// ---------------- fused: hout = shortcut + RMS(h+res)*wf; hn = LN(hout)*w2+b2 ----------------
__global__ __launch_bounds__(256) void final_ln2_kernel(const float* __restrict__ h,
    const float* __restrict__ res, const float* __restrict__ shortcut,
    const float* __restrict__ wf, const float* __restrict__ w2,
    const float* __restrict__ b2, float* __restrict__ hout,
    ushort* __restrict__ yb16)
{
    int row = blockIdx.x;
    int i0 = threadIdx.x, i1 = threadIdx.x + 256;
    size_t base = (size_t)row * Dm;
    float v0 = h[base + i0] + res[base + i0];
    float v1 = h[base + i1] + res[base + i1];
    float ss = v0 * v0 + v1 * v1;
    for (int off = 32; off; off >>= 1) ss += __shfl_down(ss, off);
    __shared__ float red[10];
    if ((threadIdx.x & 63) == 0) red[threadIdx.x >> 6] = ss;
    __syncthreads();
    if (threadIdx.x == 0) red[4] = rsqrtf((red[0] + red[1] + red[2] + red[3]) * (1.f / Dm) + 1e-5f);
    __syncthreads();
    float rs = red[4];
    float t0 = shortcut[base + i0] + v0 * rs * wf[i0];
    float t1 = shortcut[base + i1] + v1 * rs * wf[i1];
    hout[base + i0] = t0;
    hout[base + i1] = t1;
    __syncthreads();
    float s = t0 + t1, ss2 = t0 * t0 + t1 * t1;
    for (int off = 32; off; off >>= 1) { s += __shfl_down(s, off); ss2 += __shfl_down(ss2, off); }
    int wid = threadIdx.x >> 6;
    if ((threadIdx.x & 63) == 0) { red[wid] = s; red[5 + wid] = ss2; }
    __syncthreads();
    if (threadIdx.x == 0) {
        float S = red[0] + red[1] + red[2] + red[3];
        float SS = red[5] + red[6] + red[7] + red[8];
        float mu = S * (1.f / Dm);
        float var = SS * (1.f / Dm) - mu * mu;
        red[4] = mu; red[9] = rsqrtf(var + 1e-5f);
    }
    __syncthreads();
    float mu = red[4], rsig = red[9];
    yb16[base + i0] = f2bf((t0 - mu) * rsig * w2[i0] + b2[i0]);
    yb16[base + i1] = f2bf((t1 - mu) * rsig * w2[i1] + b2[i1]);
}

// ---------------- MFMA bf16 GEMM: C(M,N) = A(M,K) * W(N,K)^T ----------------
// EPI: 0 = f32 store; 1 = bf16 store; 2 = bias+gelu -> bf16; 4 = bias+addsrc -> f32
// KS>1: split-K over blockIdx.z, fp32 partials at Cout + z*split_stride (EPI must be 0)
template<int BM, int BN, int BK, int EPI, int KS = 1>
__global__ __launch_bounds__(256) void gemm_mfma(
    const ushort* __restrict__ A, int lda,
    const ushort* __restrict__ W, int K,
    void* __restrict__ Cout, int ldc,
    const float* __restrict__ bias, const float* __restrict__ addsrc,
    size_t split_stride)
{
    constexpr int ROWB  = BK * 2;            // row bytes in LDS tile
    constexpr int SMASK = (ROWB / 16) - 1;   // 16B slots per row - 1
    constexpr int KK    = BK / 32;           // mfma k-chunks per step
    constexpr int WM = BM / 2, WN = BN / 2;
    constexpr int FM = WM / 16, FN = WN / 16;
    constexpr int ISS_A = (BM * ROWB) / 4096;
    constexpr int ISS_W = (BN * ROWB) / 4096;

    __shared__ __align__(16) ushort As[BM * BK];
    __shared__ __align__(16) ushort Ws[BN * BK];

    int tid = threadIdx.x;
    int wave = tid >> 6, lane = tid & 63;
    int wr = wave >> 1, wc = wave & 1;
    int l16 = lane & 15, lk = lane >> 4;
    int bm = blockIdx.y * BM, bn = blockIdx.x * BN;

    int kbeg = 0, kend = K;
    float* coutf = (float*)Cout;
    if constexpr (KS > 1) {
        int Kper = K / KS;
        kbeg = blockIdx.z * Kper; kend = kbeg + Kper;
        coutf += split_stride * blockIdx.z;
    }

    const ushort* srcA[ISS_A];
    const ushort* srcW[ISS_W];
    #pragma unroll
    for (int s = 0; s < ISS_A; ++s) {
        int off = s * 4096 + wave * 1024 + lane * 16;
        int row = off / ROWB;
        int slot = (off % ROWB) >> 4;
        int col = ((slot ^ (row & SMASK)) << 3);
        srcA[s] = A + (size_t)(bm + row) * lda + col;
    }
    #pragma unroll
    for (int s = 0; s < ISS_W; ++s) {
        int off = s * 4096 + wave * 1024 + lane * 16;
        int row = off / ROWB;
        int slot = (off % ROWB) >> 4;
        int col = ((slot ^ (row & SMASK)) << 3);
        srcW[s] = W + (size_t)(bn + row) * K + col;
    }
    int aoff[FM][KK], woff[FN][KK];
    #pragma unroll
    for (int i = 0; i < FM; ++i) {
        int row = wr * WM + i * 16 + l16;
        #pragma unroll
        for (int kk = 0; kk < KK; ++kk)
            aoff[i][kk] = row * BK + ((((kk << 2) | lk) ^ (row & SMASK)) << 3);
    }
    #pragma unroll
    for (int j = 0; j < FN; ++j) {
        int row = wc * WN + j * 16 + l16;
        #pragma unroll
        for (int kk = 0; kk < KK; ++kk)
            woff[j][kk] = row * BK + ((((kk << 2) | lk) ^ (row & SMASK)) << 3);
    }

    f32x4 acc[FM][FN] = {};

    for (int k0 = kbeg; k0 < kend; k0 += BK) {
        #pragma unroll
        for (int s = 0; s < ISS_A; ++s)
            __builtin_amdgcn_global_load_lds(
                (const __attribute__((address_space(1))) void*)(srcA[s] + k0),
                (__attribute__((address_space(3))) void*)((char*)As + s * 4096 + wave * 1024),
                16, 0, 0);
        #pragma unroll
        for (int s = 0; s < ISS_W; ++s)
            __builtin_amdgcn_global_load_lds(
                (const __attribute__((address_space(1))) void*)(srcW[s] + k0),
                (__attribute__((address_space(3))) void*)((char*)Ws + s * 4096 + wave * 1024),
                16, 0, 0);
        __syncthreads();
        #pragma unroll
        for (int kk = 0; kk < KK; ++kk) {
            bf16x8 af[FM], wf[FN];
            #pragma unroll
            for (int i = 0; i < FM; ++i) af[i] = *(const bf16x8*)(As + aoff[i][kk]);
            #pragma unroll
            for (int j = 0; j < FN; ++j) wf[j] = *(const bf16x8*)(Ws + woff[j][kk]);
            #pragma unroll
            for (int i = 0; i < FM; ++i)
                #pragma unroll
                for (int j = 0; j < FN; ++j)
                    acc[i][j] = __builtin_amdgcn_mfma_f32_16x16x32_bf16(af[i], wf[j], acc[i][j], 0, 0, 0);
        }
        __syncthreads();
    }

    int orow0 = bm + wr * WM, ocol0 = bn + wc * WN;
    #pragma unroll
    for (int j = 0; j < FN; ++j) {
        int col = ocol0 + j * 16 + l16;
        float bj = 0.f;
        if constexpr (EPI == 2 || EPI == 4) bj = bias[col];
        #pragma unroll
        for (int i = 0; i < FM; ++i) {
            #pragma unroll
            for (int r = 0; r < 4; ++r) {
                int row = orow0 + i * 16 + lk * 4 + r;
                float v = acc[i][j][r];
                if constexpr (EPI == 0) {
                    coutf[(size_t)row * ldc + col] = v;
                } else if constexpr (EPI == 1) {
                    ((ushort*)Cout)[(size_t)row * ldc + col] = f2bf(v);
                } else if constexpr (EPI == 2) {
                    ((ushort*)Cout)[(size_t)row * ldc + col] = f2bf(act_gelu(v + bj));
                } else if constexpr (EPI == 4) {
                    ((float*)Cout)[(size_t)row * ldc + col] = v + bj + addsrc[(size_t)row * ldc + col];
                }
            }
        }
    }
}

// ---------------- x_proj finish: sum split-K partials -> dbc(B,C) fp32 + delta bf16 ----------------
__global__ __launch_bounds__(256) void xfin_kernel(
    const float* __restrict__ part, const ushort* __restrict__ wdt,
    const float* __restrict__ dtb, float* __restrict__ dbc,
    ushort* __restrict__ delta_bf)
{
    __shared__ float sdt[8][32];
    int tid = threadIdx.x;
    int t0 = blockIdx.x * 8;
    const int S = L_SEQ * 64;
    #pragma unroll
    for (int i = tid; i < 512; i += 256) {
        int tt = i >> 6, c = i & 63;
        int idx = (t0 + tt) * 64 + c;
        float s = part[idx] + part[idx + S] + part[idx + 2 * S] + part[idx + 3 * S];
        if (c < 32) sdt[tt][c] = s;
        else dbc[idx] = s;
    }
    __syncthreads();
    int d0 = tid * 4;
    bf16x8 w[4][4];
    float b4[4];
    #pragma unroll
    for (int q = 0; q < 4; ++q) {
        b4[q] = dtb[d0 + q];
        #pragma unroll
        for (int p = 0; p < 4; ++p)
            w[q][p] = *(const bf16x8*)(wdt + (size_t)(d0 + q) * 32 + p * 8);
    }
    for (int tt = 0; tt < 8; ++tt) {
        float acc[4] = { b4[0], b4[1], b4[2], b4[3] };
        #pragma unroll
        for (int p = 0; p < 4; ++p)
            #pragma unroll
            for (int e = 0; e < 8; ++e) {
                float sv = sdt[tt][p * 8 + e];
                #pragma unroll
                for (int q = 0; q < 4; ++q)
                    acc[q] = fmaf(sv, bf2f((ushort)w[q][p][e]), acc[q]);
            }
        ushort4 o;
        o.x = f2bf(act_softplus(acc[0]));
        o.y = f2bf(act_softplus(acc[1]));
        o.z = f2bf(act_softplus(acc[2]));
        o.w = f2bf(act_softplus(acc[3]));
        *(ushort4*)(delta_bf + (size_t)(t0 + tt) * DI + d0) = o;
    }
}

// ---------------- causal depthwise conv (K=4) + silu, vectorized bf16x8 ----------------
__global__ __launch_bounds__(256) void conv_silu_kernel(const ushort* __restrict__ xz,
    const float* __restrict__ cw, const float* __restrict__ cb, ushort* __restrict__ xc)
{
    int g = blockIdx.x * 256 + threadIdx.x;   // over L*DI/8
    int e = g * 8;
    int d0 = e & (DI - 1);
    int t = e >> 10;
    float acc[8];
    #pragma unroll
    for (int q = 0; q < 8; ++q) acc[q] = cb[d0 + q];
    float4 cwv[8];
    #pragma unroll
    for (int q = 0; q < 8; ++q) cwv[q] = *(const float4*)(cw + (size_t)(d0 + q) * 4);
    #pragma unroll
    for (int k = 0; k < 4; ++k) {
        int tt = t + k - 3;
        if (tt >= 0) {
            bf16x8 xv = *(const bf16x8*)(xz + (size_t)tt * (2 * DI) + d0);
            #pragma unroll
            for (int q = 0; q < 8; ++q) {
                float wk = (k == 0) ? cwv[q].x : (k == 1) ? cwv[q].y : (k == 2) ? cwv[q].z : cwv[q].w;
                acc[q] = fmaf(wk, bf2f((ushort)xv[q]), acc[q]);
            }
        }
    }
    bf16x8 o;
    #pragma unroll
    for (int q = 0; q < 8; ++q) o[q] = (short)f2bf(silu_(acc[q]));
    *(bf16x8*)(xc + e) = o;
}

// ---------------- 3-phase chunked SSM scan, 16 n-states per thread ----------------
__global__ __launch_bounds__(256) void scan_chunk_kernel(
    const ushort* __restrict__ delta, const ushort* __restrict__ u,
    const float* __restrict__ dbc, const float* __restrict__ A_log,
    float* __restrict__ hend, float* __restrict__ aprod)
{
    __shared__ float bs[LC][16];
    int tid = threadIdx.x;
    int c = blockIdx.x;
    int d = blockIdx.y * 256 + tid;
    int t0 = c * LC;
    {
        int tt = tid >> 4, nn = tid & 15;
        bs[tt][nn] = dbc[(size_t)(t0 + tt) * 64 + 32 + nn];
    }
    float A2[16];
    {
        float a[16];
        #pragma unroll
        for (int q = 0; q < 4; ++q)
            *(float4*)(a + q * 4) = ((const float4*)(A_log + (size_t)d * 16))[q];
        #pragma unroll
        for (int n = 0; n < 16; ++n)
            A2[n] = -__expf(a[n]) * 1.44269504f;   // A * log2(e)
    }
    float h[16], ap[16];
    #pragma unroll
    for (int n = 0; n < 16; ++n) { h[n] = 0.f; ap[n] = 1.f; }
    __syncthreads();
    for (int tt = 0; tt < LC; ++tt) {
        int t = t0 + tt;
        float dt_ = bf2f(delta[(size_t)t * DI + d]);
        float du = dt_ * bf2f(u[(size_t)t * DI + d]);
        #pragma unroll
        for (int n = 0; n < 16; ++n) {
            float dA = exp2f(dt_ * A2[n]);
            h[n] = fmaf(dA, h[n], du * bs[tt][n]);
            ap[n] *= dA;
        }
    }
    size_t base = ((size_t)c * DI + d) * 16;
    #pragma unroll
    for (int q = 0; q < 4; ++q) {
        ((float4*)(hend + base))[q]  = *(float4*)(h + q * 4);
        ((float4*)(aprod + base))[q] = *(float4*)(ap + q * 4);
    }
}

// Phase B: serial over chunks per (d,n), j-in-lanes (coalesced); unroll-8 for ILP.
__global__ __launch_bounds__(64) void chunk_prefix_kernel(
    const float* __restrict__ hend, float* __restrict__ aprod_hin)
{
    int j = blockIdx.x * 64 + threadIdx.x;   // over DI*16
    float h = 0.f;
    for (int cg = 0; cg < CH; cg += 8) {
        float ap[8], he[8];
        #pragma unroll
        for (int q = 0; q < 8; ++q) {
            size_t o = (size_t)(cg + q) * (DI * Nst) + j;
            ap[q] = aprod_hin[o]; he[q] = hend[o];
        }
        #pragma unroll
        for (int q = 0; q < 8; ++q) {
            size_t o = (size_t)(cg + q) * (DI * Nst) + j;
            aprod_hin[o] = h;                 // h_in for chunk cg+q
            h = fmaf(ap[q], h, he[q]);
        }
    }
}

__global__ __launch_bounds__(256) void scan_apply_kernel(
    const ushort* __restrict__ delta, const ushort* __restrict__ u,
    const float* __restrict__ dbc, const float* __restrict__ A_log,
    const float* __restrict__ Dp, const ushort* __restrict__ xz,
    const float* __restrict__ hin, ushort* __restrict__ y)
{
    __shared__ float bs[LC][16], cs[LC][16];
    int tid = threadIdx.x;
    int c = blockIdx.x;
    int d = blockIdx.y * 256 + tid;
    int t0 = c * LC;
    #pragma unroll
    for (int i = tid; i < LC * 32; i += 256) {
        int tt = i >> 5, k = i & 31;
        float v = dbc[(size_t)(t0 + tt) * 64 + 32 + k];
        if (k < 16) bs[tt][k] = v; else cs[tt][k - 16] = v;
    }
    float A2[16];
    {
        float a[16];
        #pragma unroll
        for (int q = 0; q < 4; ++q)
            *(float4*)(a + q * 4) = ((const float4*)(A_log + (size_t)d * 16))[q];
        #pragma unroll
        for (int n = 0; n < 16; ++n)
            A2[n] = -__expf(a[n]) * 1.44269504f;
    }
    float h[16];
    size_t base = ((size_t)c * DI + d) * 16;
    #pragma unroll
    for (int q = 0; q < 4; ++q)
        *(float4*)(h + q * 4) = ((const float4*)(hin + base))[q];
    float Dval = Dp[d];
    __syncthreads();
    for (int tt = 0; tt < LC; ++tt) {
        int t = t0 + tt;
        float dt_ = bf2f(delta[(size_t)t * DI + d]);
        float u_  = bf2f(u[(size_t)t * DI + d]);
        float du  = dt_ * u_;
        float acc = 0.f;
        #pragma unroll
        for (int n = 0; n < 16; ++n) {
            float dA = exp2f(dt_ * A2[n]);
            h[n] = fmaf(dA, h[n], du * bs[tt][n]);
            acc = fmaf(h[n], cs[tt][n], acc);
        }
        float z = bf2f(xz[(size_t)t * (2 * DI) + DI + d]);
        y[(size_t)t * DI + d] = f2bf((acc + u_ * Dval) * silu_(z));
    }
}

extern "C" void kernel_launch(void* const* d_in, const int* in_sizes, int n_in,
                              void* d_out, int out_size, void* d_ws, size_t ws_size,
                              hipStream_t stream)
{
    const float* hidden     = (const float*)d_in[0];
    const float* ln1_w      = (const float*)d_in[1];
    const float* ln1_b      = (const float*)d_in[2];
    const float* in_proj_w  = (const float*)d_in[3];
    const float* conv_w     = (const float*)d_in[4];
    const float* conv_b     = (const float*)d_in[5];
    const float* x_proj_w   = (const float*)d_in[6];
    const float* dt_proj_w  = (const float*)d_in[7];
    const float* dt_proj_b  = (const float*)d_in[8];
    const float* A_log      = (const float*)d_in[9];
    const float* D_param    = (const float*)d_in[10];
    const float* out_proj_w = (const float*)d_in[11];
    const float* block_norm_w = (const float*)d_in[12];
    const float* norm_f_w   = (const float*)d_in[13];
    const float* ln2_w      = (const float*)d_in[14];
    const float* ln2_b      = (const float*)d_in[15];
    const float* fc1_w      = (const float*)d_in[16];
    const float* fc1_b      = (const float*)d_in[17];
    const float* fc2_w      = (const float*)d_in[18];
    const float* fc2_b      = (const float*)d_in[19];

    char* P = (char*)d_ws;
    auto alloc = [&](size_t bytes) { char* r = P; P += (bytes + 255) & ~(size_t)255; return r; };
    float* h      = (float*)alloc((size_t)L_SEQ * Dm * 4);          // 4MB
    float* hout   = (float*)alloc((size_t)L_SEQ * Dm * 4);          // 4MB (adjacent to h)
    float* res    = (float*)alloc((size_t)L_SEQ * Dm * 4);
    float* dbc    = (float*)alloc((size_t)L_SEQ * 64 * 4);
    float* part   = (float*)alloc((size_t)4 * L_SEQ * 64 * 4);      // x_proj split-K partials
    float* aprod  = (float*)alloc((size_t)CH * DI * Nst * 4);       // 8MB; becomes hin in place
    ushort* delta_bf = (ushort*)alloc((size_t)L_SEQ * DI * 2);
    ushort* hn_bf = (ushort*)alloc((size_t)L_SEQ * Dm * 2);
    ushort* xz_bf = (ushort*)alloc((size_t)L_SEQ * 2 * DI * 2);
    ushort* xc_bf = (ushort*)alloc((size_t)L_SEQ * DI * 2);
    ushort* yb_bf = (ushort*)alloc((size_t)L_SEQ * DI * 2);
    ushort* w_in  = (ushort*)alloc((size_t)NL * 2 * DI * Dm * 2);
    ushort* w_out = (ushort*)alloc((size_t)NL * Dm * DI * 2);
    ushort* w_x   = (ushort*)alloc((size_t)NL * 64 * DI * 2);
    ushort* w_dt  = (ushort*)alloc((size_t)NL * DI * Rr * 2);
    ushort* w_fc1 = (ushort*)alloc((size_t)(4 * Dm) * Dm * 2);
    ushort* w_fc2 = (ushort*)alloc((size_t)Dm * (4 * Dm) * 2);
    float* hend = h;      // 8MB over h+hout (both dead during scan), CH*DI*16*4 = 8MB
    float* out  = (float*)d_out;

    // single fused weight cast (all layers, all 6 tensors)
    {
        int n0 = NL * 2 * DI * Dm / 4, n1 = NL * Dm * DI / 4, n2 = NL * 64 * DI / 4;
        int n3 = NL * DI * Rr / 4, n4_ = 4 * Dm * Dm / 4, n5 = Dm * 4 * Dm / 4;
        int tot = n0 + n1 + n2 + n3 + n4_ + n5;
        cast_all_kernel<<<(tot + 255) / 256, 256, 0, stream>>>(
            in_proj_w, w_in, n0, out_proj_w, w_out, n1, x_proj_w, w_x, n2,
            dt_proj_w, w_dt, n3, fc1_w, w_fc1, n4_, fc2_w, w_fc2, n5);
    }

    ln_kernel<<<L_SEQ, 256, 0, stream>>>(hidden, ln1_w, ln1_b, h);

    dim3 gscan(CH, DI / 256);   // 128 x 4 = 512 blocks
    for (int i = 0; i < NL; ++i) {
        add_rms_kernel<<<L_SEQ, 256, 0, stream>>>(h, i ? res : nullptr, res,
                                                  block_norm_w + i * Dm, hn_bf);
        // in_proj: M=2048 N=2048 K=512 -> bf16 xz
        gemm_mfma<128, 128, 128, 1><<<dim3(2 * DI / 128, L_SEQ / 128), 256, 0, stream>>>(
            hn_bf, Dm, w_in + (size_t)i * 2 * DI * Dm, Dm, xz_bf, 2 * DI, nullptr, nullptr, 0);
        conv_silu_kernel<<<(L_SEQ * DI / 8) / 256, 256, 0, stream>>>(
            xz_bf, conv_w + i * DI * Kc, conv_b + i * DI, xc_bf);
        // x_proj: M=2048 N=64 K=1024, split-K=4 -> fp32 partials
        gemm_mfma<64, 64, 64, 0, 4><<<dim3(1, L_SEQ / 64, 4), 256, 0, stream>>>(
            xc_bf, DI, w_x + (size_t)i * 64 * DI, DI, part, 64, nullptr, nullptr,
            (size_t)L_SEQ * 64);
        // finish: dbc(B,C) + delta = softplus(dt @ w_dt^T + b) -> bf16
        xfin_kernel<<<L_SEQ / 8, 256, 0, stream>>>(part, w_dt + (size_t)i * DI * Rr,
                                        dt_proj_b + i * DI, dbc, delta_bf);
        // 3-phase chunked scan
        scan_chunk_kernel<<<gscan, 256, 0, stream>>>(delta_bf, xc_bf, dbc,
                                        A_log + (size_t)i * DI * Nst, hend, aprod);
        chunk_prefix_kernel<<<(DI * Nst) / 64, 64, 0, stream>>>(hend, aprod);
        scan_apply_kernel<<<gscan, 256, 0, stream>>>(delta_bf, xc_bf, dbc,
                                        A_log + (size_t)i * DI * Nst,
                                        D_param + i * DI, xz_bf, aprod, yb_bf);
        // out_proj: M=2048 N=512 K=1024 -> fp32 h
        gemm_mfma<64, 64, 128, 0><<<dim3(Dm / 64, L_SEQ / 64), 256, 0, stream>>>(
            yb_bf, DI, w_out + (size_t)i * Dm * DI, DI, h, Dm, nullptr, nullptr, 0);
    }

    final_ln2_kernel<<<L_SEQ, 256, 0, stream>>>(h, res, hidden, norm_f_w,
                                                ln2_w, ln2_b, hout, hn_bf);
    // fc1: M=2048 N=2048 K=512, bias+gelu -> bf16 (reuse xz_bf)
    gemm_mfma<128, 128, 128, 2><<<dim3(2048 / 128, L_SEQ / 128), 256, 0, stream>>>(
        hn_bf, Dm, w_fc1, Dm, xz_bf, 2048, fc1_b, nullptr, 0);
    // fc2: M=2048 N=512 K=2048, bias+add(hout) -> fp32 out
    gemm_mfma<64, 64, 128, 4><<<dim3(Dm / 64, L_SEQ / 64), 256, 0, stream>>>(
        xz_bf, 2048, w_fc2, 2048, out, Dm, fc2_b, hout, 0);
}

// Round 10
// 445.401 us; speedup vs baseline: 1.2852x; 1.0259x over previous
//
#include <hip/hip_runtime.h>
#include <hip/hip_bf16.h>
#include <math.h>

#define L_SEQ 2048
#define Dm    512
#define DI    1024
#define Nst   16
#define Kc    4
#define Rr    32
#define NL    4
#define CH    128
#define LC    (L_SEQ / CH)   // 16

typedef __attribute__((ext_vector_type(8))) short bf16x8;
typedef __attribute__((ext_vector_type(4))) float f32x4;

// ---------------- helpers ----------------
__device__ __forceinline__ float act_softplus(float x) {
    return fmaxf(x, 0.f) + log1pf(__expf(-fabsf(x)));
}
__device__ __forceinline__ float act_gelu(float x) {
    float c = 0.7978845608028654f * (x + 0.044715f * x * x * x);
    float t = 1.f - 2.f / (__expf(2.f * c) + 1.f);   // tanh(c)
    return 0.5f * x * (1.f + t);
}
__device__ __forceinline__ float silu_(float x) {
    return x / (1.f + __expf(-x));
}
__device__ __forceinline__ ushort f2bf(float f) {
    union { float f; unsigned u; } c; c.f = f;
    unsigned r = c.u + 0x7fffu + ((c.u >> 16) & 1u);
    return (ushort)(r >> 16);
}
__device__ __forceinline__ float bf2f(ushort u) {
    union { unsigned u; float f; } c; c.u = ((unsigned)u) << 16;
    return c.f;
}
__device__ __forceinline__ float wave_sum(float v) {
    #pragma unroll
    for (int off = 32; off; off >>= 1) v += __shfl_xor(v, off);
    return v;
}

// ---------------- one-shot weight cast f32 -> bf16 (all 6 tensors) ----------------
__global__ __launch_bounds__(256) void cast_all_kernel(
    const float* __restrict__ s0, ushort* __restrict__ d0, int n0,
    const float* __restrict__ s1, ushort* __restrict__ d1, int n1,
    const float* __restrict__ s2, ushort* __restrict__ d2, int n2,
    const float* __restrict__ s3, ushort* __restrict__ d3, int n3,
    const float* __restrict__ s4, ushort* __restrict__ d4, int n4_,
    const float* __restrict__ s5, ushort* __restrict__ d5, int n5)
{
    int i = blockIdx.x * 256 + threadIdx.x;
    const float* s; ushort* d;
    if (i < n0) { s = s0; d = d0; }
    else { i -= n0; if (i < n1) { s = s1; d = d1; }
    else { i -= n1; if (i < n2) { s = s2; d = d2; }
    else { i -= n2; if (i < n3) { s = s3; d = d3; }
    else { i -= n3; if (i < n4_) { s = s4; d = d4; }
    else { i -= n4_; if (i < n5) { s = s5; d = d5; } else return; } } } } }
    float4 v = ((const float4*)s)[i];
    ushort4 o;
    o.x = f2bf(v.x); o.y = f2bf(v.y); o.z = f2bf(v.z); o.w = f2bf(v.w);
    ((ushort4*)d)[i] = o;
}

// ---------------- fused LN1 + layer-0 RMS: res = LN(x); hn = RMS(res)*rw ----------------
// one 64-lane wave per row of 512 (8 elems/lane), butterfly reduce, no LDS
__global__ __launch_bounds__(256) void ln_rms_kernel(const float* __restrict__ x,
    const float* __restrict__ w, const float* __restrict__ b,
    const float* __restrict__ rw, float* __restrict__ res,
    ushort* __restrict__ hn_bf)
{
    int lane = threadIdx.x & 63, wv = threadIdx.x >> 6;
    int row = blockIdx.x * 4 + wv;
    size_t base = (size_t)row * Dm + lane * 8;
    float v[8];
    *(float4*)(v)     = *(const float4*)(x + base);
    *(float4*)(v + 4) = *(const float4*)(x + base + 4);
    float s = 0.f, ss = 0.f;
    #pragma unroll
    for (int q = 0; q < 8; ++q) { s += v[q]; ss += v[q] * v[q]; }
    s = wave_sum(s); ss = wave_sum(ss);
    float mu = s * (1.f / Dm);
    float rs = rsqrtf(ss * (1.f / Dm) - mu * mu + 1e-5f);
    float wv8[8], bv8[8], rv8[8];
    *(float4*)(wv8)     = *(const float4*)(w + lane * 8);
    *(float4*)(wv8 + 4) = *(const float4*)(w + lane * 8 + 4);
    *(float4*)(bv8)     = *(const float4*)(b + lane * 8);
    *(float4*)(bv8 + 4) = *(const float4*)(b + lane * 8 + 4);
    *(float4*)(rv8)     = *(const float4*)(rw + lane * 8);
    *(float4*)(rv8 + 4) = *(const float4*)(rw + lane * 8 + 4);
    float o[8], ss2 = 0.f;
    #pragma unroll
    for (int q = 0; q < 8; ++q) {
        o[q] = (v[q] - mu) * rs * wv8[q] + bv8[q];
        ss2 += o[q] * o[q];
    }
    *(float4*)(res + base)     = *(float4*)(o);
    *(float4*)(res + base + 4) = *(float4*)(o + 4);
    ss2 = wave_sum(ss2);
    float rr = rsqrtf(ss2 * (1.f / Dm) + 1e-5f);
    bf16x8 hb;
    #pragma unroll
    for (int q = 0; q < 8; ++q) hb[q] = (short)f2bf(o[q] * rr * rv8[q]);
    *(bf16x8*)(hn_bf + base) = hb;
}

// ---------------- residual add + RMSNorm: res += h(bf16); hn = RMS(res)*w ----------------
__global__ __launch_bounds__(256) void add_rms_kernel(const ushort* __restrict__ hb,
    float* __restrict__ res, const float* __restrict__ w, ushort* __restrict__ rms_out)
{
    int lane = threadIdx.x & 63, wv = threadIdx.x >> 6;
    int row = blockIdx.x * 4 + wv;
    size_t base = (size_t)row * Dm + lane * 8;
    bf16x8 hv = *(const bf16x8*)(hb + base);
    float v[8];
    *(float4*)(v)     = *(const float4*)(res + base);
    *(float4*)(v + 4) = *(const float4*)(res + base + 4);
    float ss = 0.f;
    #pragma unroll
    for (int q = 0; q < 8; ++q) {
        v[q] += bf2f((ushort)hv[q]);
        ss += v[q] * v[q];
    }
    *(float4*)(res + base)     = *(float4*)(v);
    *(float4*)(res + base + 4) = *(float4*)(v + 4);
    ss = wave_sum(ss);
    float rr = rsqrtf(ss * (1.f / Dm) + 1e-5f);
    float wv8[8];
    *(float4*)(wv8)     = *(const float4*)(w + lane * 8);
    *(float4*)(wv8 + 4) = *(const float4*)(w + lane * 8 + 4);
    bf16x8 ob;
    #pragma unroll
    for (int q = 0; q < 8; ++q) ob[q] = (short)f2bf(v[q] * rr * wv8[q]);
    *(bf16x8*)(rms_out + base) = ob;
}

// ---------------- fused: hout = shortcut + RMS(h+res)*wf; hn = LN(hout)*w2+b2 ----------------
__global__ __launch_bounds__(256) void final_ln2_kernel(const ushort* __restrict__ hb,
    const float* __restrict__ res, const float* __restrict__ shortcut,
    const float* __restrict__ wf, const float* __restrict__ w2,
    const float* __restrict__ b2, float* __restrict__ hout,
    ushort* __restrict__ yb16)
{
    int lane = threadIdx.x & 63, wv = threadIdx.x >> 6;
    int row = blockIdx.x * 4 + wv;
    size_t base = (size_t)row * Dm + lane * 8;
    bf16x8 hv = *(const bf16x8*)(hb + base);
    float v[8];
    *(float4*)(v)     = *(const float4*)(res + base);
    *(float4*)(v + 4) = *(const float4*)(res + base + 4);
    float ss = 0.f;
    #pragma unroll
    for (int q = 0; q < 8; ++q) {
        v[q] += bf2f((ushort)hv[q]);
        ss += v[q] * v[q];
    }
    ss = wave_sum(ss);
    float rs = rsqrtf(ss * (1.f / Dm) + 1e-5f);
    float sc[8], wf8[8];
    *(float4*)(sc)     = *(const float4*)(shortcut + base);
    *(float4*)(sc + 4) = *(const float4*)(shortcut + base + 4);
    *(float4*)(wf8)     = *(const float4*)(wf + lane * 8);
    *(float4*)(wf8 + 4) = *(const float4*)(wf + lane * 8 + 4);
    float t[8], s2 = 0.f, ss2 = 0.f;
    #pragma unroll
    for (int q = 0; q < 8; ++q) {
        t[q] = sc[q] + v[q] * rs * wf8[q];
        s2 += t[q]; ss2 += t[q] * t[q];
    }
    *(float4*)(hout + base)     = *(float4*)(t);
    *(float4*)(hout + base + 4) = *(float4*)(t + 4);
    s2 = wave_sum(s2); ss2 = wave_sum(ss2);
    float mu = s2 * (1.f / Dm);
    float rsig = rsqrtf(ss2 * (1.f / Dm) - mu * mu + 1e-5f);
    float w28[8], b28[8];
    *(float4*)(w28)     = *(const float4*)(w2 + lane * 8);
    *(float4*)(w28 + 4) = *(const float4*)(w2 + lane * 8 + 4);
    *(float4*)(b28)     = *(const float4*)(b2 + lane * 8);
    *(float4*)(b28 + 4) = *(const float4*)(b2 + lane * 8 + 4);
    bf16x8 ob;
    #pragma unroll
    for (int q = 0; q < 8; ++q) ob[q] = (short)f2bf((t[q] - mu) * rsig * w28[q] + b28[q]);
    *(bf16x8*)(yb16 + base) = ob;
}

// ---------------- MFMA bf16 GEMM: C(M,N) = A(M,K) * W(N,K)^T ----------------
// EPI: 0 = f32 store; 1 = bf16 store; 2 = bias+gelu -> bf16; 4 = bias+addsrc -> f32
// KS>1: split-K over blockIdx.z, fp32 partials at Cout + z*split_stride (EPI must be 0)
template<int BM, int BN, int BK, int EPI, int KS = 1>
__global__ __launch_bounds__(256) void gemm_mfma(
    const ushort* __restrict__ A, int lda,
    const ushort* __restrict__ W, int K,
    void* __restrict__ Cout, int ldc,
    const float* __restrict__ bias, const float* __restrict__ addsrc,
    size_t split_stride)
{
    constexpr int ROWB  = BK * 2;            // row bytes in LDS tile
    constexpr int SMASK = (ROWB / 16) - 1;   // 16B slots per row - 1
    constexpr int KK    = BK / 32;           // mfma k-chunks per step
    constexpr int WM = BM / 2, WN = BN / 2;
    constexpr int FM = WM / 16, FN = WN / 16;
    constexpr int ISS_A = (BM * ROWB) / 4096;
    constexpr int ISS_W = (BN * ROWB) / 4096;

    __shared__ __align__(16) ushort As[BM * BK];
    __shared__ __align__(16) ushort Ws[BN * BK];

    int tid = threadIdx.x;
    int wave = tid >> 6, lane = tid & 63;
    int wr = wave >> 1, wc = wave & 1;
    int l16 = lane & 15, lk = lane >> 4;
    int bm = blockIdx.y * BM, bn = blockIdx.x * BN;

    int kbeg = 0, kend = K;
    float* coutf = (float*)Cout;
    if constexpr (KS > 1) {
        int Kper = K / KS;
        kbeg = blockIdx.z * Kper; kend = kbeg + Kper;
        coutf += split_stride * blockIdx.z;
    }

    const ushort* srcA[ISS_A];
    const ushort* srcW[ISS_W];
    #pragma unroll
    for (int s = 0; s < ISS_A; ++s) {
        int off = s * 4096 + wave * 1024 + lane * 16;
        int row = off / ROWB;
        int slot = (off % ROWB) >> 4;
        int col = ((slot ^ (row & SMASK)) << 3);
        srcA[s] = A + (size_t)(bm + row) * lda + col;
    }
    #pragma unroll
    for (int s = 0; s < ISS_W; ++s) {
        int off = s * 4096 + wave * 1024 + lane * 16;
        int row = off / ROWB;
        int slot = (off % ROWB) >> 4;
        int col = ((slot ^ (row & SMASK)) << 3);
        srcW[s] = W + (size_t)(bn + row) * K + col;
    }
    int aoff[FM][KK], woff[FN][KK];
    #pragma unroll
    for (int i = 0; i < FM; ++i) {
        int row = wr * WM + i * 16 + l16;
        #pragma unroll
        for (int kk = 0; kk < KK; ++kk)
            aoff[i][kk] = row * BK + ((((kk << 2) | lk) ^ (row & SMASK)) << 3);
    }
    #pragma unroll
    for (int j = 0; j < FN; ++j) {
        int row = wc * WN + j * 16 + l16;
        #pragma unroll
        for (int kk = 0; kk < KK; ++kk)
            woff[j][kk] = row * BK + ((((kk << 2) | lk) ^ (row & SMASK)) << 3);
    }

    f32x4 acc[FM][FN] = {};

    for (int k0 = kbeg; k0 < kend; k0 += BK) {
        #pragma unroll
        for (int s = 0; s < ISS_A; ++s)
            __builtin_amdgcn_global_load_lds(
                (const __attribute__((address_space(1))) void*)(srcA[s] + k0),
                (__attribute__((address_space(3))) void*)((char*)As + s * 4096 + wave * 1024),
                16, 0, 0);
        #pragma unroll
        for (int s = 0; s < ISS_W; ++s)
            __builtin_amdgcn_global_load_lds(
                (const __attribute__((address_space(1))) void*)(srcW[s] + k0),
                (__attribute__((address_space(3))) void*)((char*)Ws + s * 4096 + wave * 1024),
                16, 0, 0);
        __syncthreads();
        #pragma unroll
        for (int kk = 0; kk < KK; ++kk) {
            bf16x8 af[FM], wf[FN];
            #pragma unroll
            for (int i = 0; i < FM; ++i) af[i] = *(const bf16x8*)(As + aoff[i][kk]);
            #pragma unroll
            for (int j = 0; j < FN; ++j) wf[j] = *(const bf16x8*)(Ws + woff[j][kk]);
            #pragma unroll
            for (int i = 0; i < FM; ++i)
                #pragma unroll
                for (int j = 0; j < FN; ++j)
                    acc[i][j] = __builtin_amdgcn_mfma_f32_16x16x32_bf16(af[i], wf[j], acc[i][j], 0, 0, 0);
        }
        __syncthreads();
    }

    int orow0 = bm + wr * WM, ocol0 = bn + wc * WN;
    #pragma unroll
    for (int j = 0; j < FN; ++j) {
        int col = ocol0 + j * 16 + l16;
        float bj = 0.f;
        if constexpr (EPI == 2 || EPI == 4) bj = bias[col];
        #pragma unroll
        for (int i = 0; i < FM; ++i) {
            #pragma unroll
            for (int r = 0; r < 4; ++r) {
                int row = orow0 + i * 16 + lk * 4 + r;
                float v = acc[i][j][r];
                if constexpr (EPI == 0) {
                    coutf[(size_t)row * ldc + col] = v;
                } else if constexpr (EPI == 1) {
                    ((ushort*)Cout)[(size_t)row * ldc + col] = f2bf(v);
                } else if constexpr (EPI == 2) {
                    ((ushort*)Cout)[(size_t)row * ldc + col] = f2bf(act_gelu(v + bj));
                } else if constexpr (EPI == 4) {
                    ((float*)Cout)[(size_t)row * ldc + col] = v + bj + addsrc[(size_t)row * ldc + col];
                }
            }
        }
    }
}

// ---------------- x_proj finish: sum split-K partials -> dbc(B,C) fp32 + delta bf16 ----------------
__global__ __launch_bounds__(256) void xfin_kernel(
    const float* __restrict__ part, const ushort* __restrict__ wdt,
    const float* __restrict__ dtb, float* __restrict__ dbc,
    ushort* __restrict__ delta_bf)
{
    __shared__ float sdt[8][32];
    int tid = threadIdx.x;
    int t0 = blockIdx.x * 8;
    const int S = L_SEQ * 64;
    #pragma unroll
    for (int i = tid; i < 512; i += 256) {
        int tt = i >> 6, c = i & 63;
        int idx = (t0 + tt) * 64 + c;
        float s = part[idx] + part[idx + S] + part[idx + 2 * S] + part[idx + 3 * S];
        if (c < 32) sdt[tt][c] = s;
        else dbc[idx] = s;
    }
    __syncthreads();
    int d0 = tid * 4;
    bf16x8 w[4][4];
    float b4[4];
    #pragma unroll
    for (int q = 0; q < 4; ++q) {
        b4[q] = dtb[d0 + q];
        #pragma unroll
        for (int p = 0; p < 4; ++p)
            w[q][p] = *(const bf16x8*)(wdt + (size_t)(d0 + q) * 32 + p * 8);
    }
    for (int tt = 0; tt < 8; ++tt) {
        float acc[4] = { b4[0], b4[1], b4[2], b4[3] };
        #pragma unroll
        for (int p = 0; p < 4; ++p)
            #pragma unroll
            for (int e = 0; e < 8; ++e) {
                float sv = sdt[tt][p * 8 + e];
                #pragma unroll
                for (int q = 0; q < 4; ++q)
                    acc[q] = fmaf(sv, bf2f((ushort)w[q][p][e]), acc[q]);
            }
        ushort4 o;
        o.x = f2bf(act_softplus(acc[0]));
        o.y = f2bf(act_softplus(acc[1]));
        o.z = f2bf(act_softplus(acc[2]));
        o.w = f2bf(act_softplus(acc[3]));
        *(ushort4*)(delta_bf + (size_t)(t0 + tt) * DI + d0) = o;
    }
}

// ---------------- causal depthwise conv (K=4) + silu, vectorized bf16x8 ----------------
__global__ __launch_bounds__(256) void conv_silu_kernel(const ushort* __restrict__ xz,
    const float* __restrict__ cw, const float* __restrict__ cb, ushort* __restrict__ xc)
{
    int g = blockIdx.x * 256 + threadIdx.x;   // over L*DI/8
    int e = g * 8;
    int d0 = e & (DI - 1);
    int t = e >> 10;
    float acc[8];
    #pragma unroll
    for (int q = 0; q < 8; ++q) acc[q] = cb[d0 + q];
    float4 cwv[8];
    #pragma unroll
    for (int q = 0; q < 8; ++q) cwv[q] = *(const float4*)(cw + (size_t)(d0 + q) * 4);
    #pragma unroll
    for (int k = 0; k < 4; ++k) {
        int tt = t + k - 3;
        if (tt >= 0) {
            bf16x8 xv = *(const bf16x8*)(xz + (size_t)tt * (2 * DI) + d0);
            #pragma unroll
            for (int q = 0; q < 8; ++q) {
                float wk = (k == 0) ? cwv[q].x : (k == 1) ? cwv[q].y : (k == 2) ? cwv[q].z : cwv[q].w;
                acc[q] = fmaf(wk, bf2f((ushort)xv[q]), acc[q]);
            }
        }
    }
    bf16x8 o;
    #pragma unroll
    for (int q = 0; q < 8; ++q) o[q] = (short)f2bf(silu_(acc[q]));
    *(bf16x8*)(xc + e) = o;
}

// ---------------- 3-phase chunked SSM scan, 16 n-states per thread ----------------
__global__ __launch_bounds__(256) void scan_chunk_kernel(
    const ushort* __restrict__ delta, const ushort* __restrict__ u,
    const float* __restrict__ dbc, const float* __restrict__ A_log,
    float* __restrict__ hend, float* __restrict__ aprod)
{
    __shared__ float bs[LC][16];
    int tid = threadIdx.x;
    int c = blockIdx.x;
    int d = blockIdx.y * 256 + tid;
    int t0 = c * LC;
    {
        int tt = tid >> 4, nn = tid & 15;
        bs[tt][nn] = dbc[(size_t)(t0 + tt) * 64 + 32 + nn];
    }
    float A2[16];
    {
        float a[16];
        #pragma unroll
        for (int q = 0; q < 4; ++q)
            *(float4*)(a + q * 4) = ((const float4*)(A_log + (size_t)d * 16))[q];
        #pragma unroll
        for (int n = 0; n < 16; ++n)
            A2[n] = -__expf(a[n]) * 1.44269504f;   // A * log2(e)
    }
    float h[16], ap[16];
    #pragma unroll
    for (int n = 0; n < 16; ++n) { h[n] = 0.f; ap[n] = 1.f; }
    __syncthreads();
    for (int tt = 0; tt < LC; ++tt) {
        int t = t0 + tt;
        float dt_ = bf2f(delta[(size_t)t * DI + d]);
        float du = dt_ * bf2f(u[(size_t)t * DI + d]);
        #pragma unroll
        for (int n = 0; n < 16; ++n) {
            float dA = exp2f(dt_ * A2[n]);
            h[n] = fmaf(dA, h[n], du * bs[tt][n]);
            ap[n] *= dA;
        }
    }
    size_t base = ((size_t)c * DI + d) * 16;
    #pragma unroll
    for (int q = 0; q < 4; ++q) {
        ((float4*)(hend + base))[q]  = *(float4*)(h + q * 4);
        ((float4*)(aprod + base))[q] = *(float4*)(ap + q * 4);
    }
}

// Phase B: serial over chunks per (d,n), j-in-lanes (coalesced); unroll-8 for ILP.
__global__ __launch_bounds__(64) void chunk_prefix_kernel(
    const float* __restrict__ hend, float* __restrict__ aprod_hin)
{
    int j = blockIdx.x * 64 + threadIdx.x;   // over DI*16
    float h = 0.f;
    for (int cg = 0; cg < CH; cg += 8) {
        float ap[8], he[8];
        #pragma unroll
        for (int q = 0; q < 8; ++q) {
            size_t o = (size_t)(cg + q) * (DI * Nst) + j;
            ap[q] = aprod_hin[o]; he[q] = hend[o];
        }
        #pragma unroll
        for (int q = 0; q < 8; ++q) {
            size_t o = (size_t)(cg + q) * (DI * Nst) + j;
            aprod_hin[o] = h;                 // h_in for chunk cg+q
            h = fmaf(ap[q], h, he[q]);
        }
    }
}

__global__ __launch_bounds__(256) void scan_apply_kernel(
    const ushort* __restrict__ delta, const ushort* __restrict__ u,
    const float* __restrict__ dbc, const float* __restrict__ A_log,
    const float* __restrict__ Dp, const ushort* __restrict__ xz,
    const float* __restrict__ hin, ushort* __restrict__ y)
{
    __shared__ float bs[LC][16], cs[LC][16];
    int tid = threadIdx.x;
    int c = blockIdx.x;
    int d = blockIdx.y * 256 + tid;
    int t0 = c * LC;
    #pragma unroll
    for (int i = tid; i < LC * 32; i += 256) {
        int tt = i >> 5, k = i & 31;
        float v = dbc[(size_t)(t0 + tt) * 64 + 32 + k];
        if (k < 16) bs[tt][k] = v; else cs[tt][k - 16] = v;
    }
    float A2[16];
    {
        float a[16];
        #pragma unroll
        for (int q = 0; q < 4; ++q)
            *(float4*)(a + q * 4) = ((const float4*)(A_log + (size_t)d * 16))[q];
        #pragma unroll
        for (int n = 0; n < 16; ++n)
            A2[n] = -__expf(a[n]) * 1.44269504f;
    }
    float h[16];
    size_t base = ((size_t)c * DI + d) * 16;
    #pragma unroll
    for (int q = 0; q < 4; ++q)
        *(float4*)(h + q * 4) = ((const float4*)(hin + base))[q];
    float Dval = Dp[d];
    __syncthreads();
    for (int tt = 0; tt < LC; ++tt) {
        int t = t0 + tt;
        float dt_ = bf2f(delta[(size_t)t * DI + d]);
        float u_  = bf2f(u[(size_t)t * DI + d]);
        float du  = dt_ * u_;
        float acc = 0.f;
        #pragma unroll
        for (int n = 0; n < 16; ++n) {
            float dA = exp2f(dt_ * A2[n]);
            h[n] = fmaf(dA, h[n], du * bs[tt][n]);
            acc = fmaf(h[n], cs[tt][n], acc);
        }
        float z = bf2f(xz[(size_t)t * (2 * DI) + DI + d]);
        y[(size_t)t * DI + d] = f2bf((acc + u_ * Dval) * silu_(z));
    }
}

extern "C" void kernel_launch(void* const* d_in, const int* in_sizes, int n_in,
                              void* d_out, int out_size, void* d_ws, size_t ws_size,
                              hipStream_t stream)
{
    const float* hidden     = (const float*)d_in[0];
    const float* ln1_w      = (const float*)d_in[1];
    const float* ln1_b      = (const float*)d_in[2];
    const float* in_proj_w  = (const float*)d_in[3];
    const float* conv_w     = (const float*)d_in[4];
    const float* conv_b     = (const float*)d_in[5];
    const float* x_proj_w   = (const float*)d_in[6];
    const float* dt_proj_w  = (const float*)d_in[7];
    const float* dt_proj_b  = (const float*)d_in[8];
    const float* A_log      = (const float*)d_in[9];
    const float* D_param    = (const float*)d_in[10];
    const float* out_proj_w = (const float*)d_in[11];
    const float* block_norm_w = (const float*)d_in[12];
    const float* norm_f_w   = (const float*)d_in[13];
    const float* ln2_w      = (const float*)d_in[14];
    const float* ln2_b      = (const float*)d_in[15];
    const float* fc1_w      = (const float*)d_in[16];
    const float* fc1_b      = (const float*)d_in[17];
    const float* fc2_w      = (const float*)d_in[18];
    const float* fc2_b      = (const float*)d_in[19];

    char* P = (char*)d_ws;
    auto alloc = [&](size_t bytes) { char* r = P; P += (bytes + 255) & ~(size_t)255; return r; };
    float* hout   = (float*)alloc((size_t)L_SEQ * Dm * 4);
    float* res    = (float*)alloc((size_t)L_SEQ * Dm * 4);
    float* dbc    = (float*)alloc((size_t)L_SEQ * 64 * 4);
    float* part   = (float*)alloc((size_t)4 * L_SEQ * 64 * 4);      // x_proj split-K partials
    float* hend   = (float*)alloc((size_t)CH * DI * Nst * 4);       // 8MB
    float* aprod  = (float*)alloc((size_t)CH * DI * Nst * 4);       // 8MB; becomes hin in place
    ushort* h_bf  = (ushort*)alloc((size_t)L_SEQ * Dm * 2);
    ushort* delta_bf = (ushort*)alloc((size_t)L_SEQ * DI * 2);
    ushort* hn_bf = (ushort*)alloc((size_t)L_SEQ * Dm * 2);
    ushort* xz_bf = (ushort*)alloc((size_t)L_SEQ * 2 * DI * 2);
    ushort* xc_bf = (ushort*)alloc((size_t)L_SEQ * DI * 2);
    ushort* yb_bf = (ushort*)alloc((size_t)L_SEQ * DI * 2);
    ushort* w_in  = (ushort*)alloc((size_t)NL * 2 * DI * Dm * 2);
    ushort* w_out = (ushort*)alloc((size_t)NL * Dm * DI * 2);
    ushort* w_x   = (ushort*)alloc((size_t)NL * 64 * DI * 2);
    ushort* w_dt  = (ushort*)alloc((size_t)NL * DI * Rr * 2);
    ushort* w_fc1 = (ushort*)alloc((size_t)(4 * Dm) * Dm * 2);
    ushort* w_fc2 = (ushort*)alloc((size_t)Dm * (4 * Dm) * 2);
    float* out  = (float*)d_out;

    // single fused weight cast (all layers, all 6 tensors)
    {
        int n0 = NL * 2 * DI * Dm / 4, n1 = NL * Dm * DI / 4, n2 = NL * 64 * DI / 4;
        int n3 = NL * DI * Rr / 4, n4_ = 4 * Dm * Dm / 4, n5 = Dm * 4 * Dm / 4;
        int tot = n0 + n1 + n2 + n3 + n4_ + n5;
        cast_all_kernel<<<(tot + 255) / 256, 256, 0, stream>>>(
            in_proj_w, w_in, n0, out_proj_w, w_out, n1, x_proj_w, w_x, n2,
            dt_proj_w, w_dt, n3, fc1_w, w_fc1, n4_, fc2_w, w_fc2, n5);
    }

    // fused LN1 + layer-0 residual/RMS: res = LN(hidden), hn = RMS(res)*bw0
    ln_rms_kernel<<<L_SEQ / 4, 256, 0, stream>>>(hidden, ln1_w, ln1_b,
                                                 block_norm_w, res, hn_bf);

    dim3 gscan(CH, DI / 256);   // 128 x 4 = 512 blocks
    for (int i = 0; i < NL; ++i) {
        if (i) add_rms_kernel<<<L_SEQ / 4, 256, 0, stream>>>(h_bf, res,
                                                  block_norm_w + i * Dm, hn_bf);
        // in_proj: M=2048 N=2048 K=512 -> bf16 xz
        gemm_mfma<128, 128, 128, 1><<<dim3(2 * DI / 128, L_SEQ / 128), 256, 0, stream>>>(
            hn_bf, Dm, w_in + (size_t)i * 2 * DI * Dm, Dm, xz_bf, 2 * DI, nullptr, nullptr, 0);
        conv_silu_kernel<<<(L_SEQ * DI / 8) / 256, 256, 0, stream>>>(
            xz_bf, conv_w + i * DI * Kc, conv_b + i * DI, xc_bf);
        // x_proj: M=2048 N=64 K=1024, split-K=4 -> fp32 partials
        gemm_mfma<64, 64, 64, 0, 4><<<dim3(1, L_SEQ / 64, 4), 256, 0, stream>>>(
            xc_bf, DI, w_x + (size_t)i * 64 * DI, DI, part, 64, nullptr, nullptr,
            (size_t)L_SEQ * 64);
        // finish: dbc(B,C) + delta = softplus(dt @ w_dt^T + b) -> bf16
        xfin_kernel<<<L_SEQ / 8, 256, 0, stream>>>(part, w_dt + (size_t)i * DI * Rr,
                                        dt_proj_b + i * DI, dbc, delta_bf);
        // 3-phase chunked scan
        scan_chunk_kernel<<<gscan, 256, 0, stream>>>(delta_bf, xc_bf, dbc,
                                        A_log + (size_t)i * DI * Nst, hend, aprod);
        chunk_prefix_kernel<<<(DI * Nst) / 64, 64, 0, stream>>>(hend, aprod);
        scan_apply_kernel<<<gscan, 256, 0, stream>>>(delta_bf, xc_bf, dbc,
                                        A_log + (size_t)i * DI * Nst,
                                        D_param + i * DI, xz_bf, aprod, yb_bf);
        // out_proj: M=2048 N=512 K=1024 -> bf16 h
        gemm_mfma<64, 64, 128, 1><<<dim3(Dm / 64, L_SEQ / 64), 256, 0, stream>>>(
            yb_bf, DI, w_out + (size_t)i * Dm * DI, DI, h_bf, Dm, nullptr, nullptr, 0);
    }

    final_ln2_kernel<<<L_SEQ / 4, 256, 0, stream>>>(h_bf, res, hidden, norm_f_w,
                                                ln2_w, ln2_b, hout, hn_bf);
    // fc1: M=2048 N=2048 K=512, bias+gelu -> bf16 (reuse xz_bf)
    gemm_mfma<128, 128, 128, 2><<<dim3(2048 / 128, L_SEQ / 128), 256, 0, stream>>>(
        hn_bf, Dm, w_fc1, Dm, xz_bf, 2048, fc1_b, nullptr, 0);
    // fc2: M=2048 N=512 K=2048, bias+add(hout) -> fp32 out
    gemm_mfma<64, 64, 128, 4><<<dim3(Dm / 64, L_SEQ / 64), 256, 0, stream>>>(
        xz_bf, 2048, w_fc2, 2048, out, Dm, fc2_b, hout, 0);
}